// Round 5
// baseline (68.701 us; speedup 1.0000x reference)
//
#include <hip/hip_runtime.h>
#include <hip/hip_bf16.h>
#include <stdint.h>

#define NROWS 8192
#define BROWS 4096
#define SQRT_SCALE 3.7982826f   // sqrt((1/T)*log2(e)), T=0.1
#define LN2 0.6931471805599453f
#define NBLK 1056               // sum_{it=0}^{63} ceil((8192-128it)/256)

typedef __attribute__((ext_vector_type(8))) short bf16x8;
typedef __attribute__((ext_vector_type(16))) float f32x16;

__device__ inline void gload_lds16(const void* g, void* l) {
  __builtin_amdgcn_global_load_lds((const __attribute__((address_space(1))) void*)g,
                                   (__attribute__((address_space(3))) void*)l,
                                   16, 0, 0);
}

__device__ inline unsigned short f2bf(float x) {
  __hip_bfloat16 h = __float2bfloat16(x);
  return __builtin_bit_cast(unsigned short, h);
}

// Kernel A: L2-normalize rows, scale by sqrt((1/T)log2e), -> bf16 reps; zero denom/out.
__global__ __launch_bounds__(256) void knorm(const float* __restrict__ zi,
                                             const float* __restrict__ zj,
                                             unsigned short* __restrict__ reps,
                                             float* __restrict__ denom,
                                             float* __restrict__ out) {
  int w = threadIdx.x >> 6, l = threadIdx.x & 63;
  int row = blockIdx.x * 4 + w;
  const float* src = (row < BROWS) ? (zi + (size_t)row * 256)
                                   : (zj + (size_t)(row - BROWS) * 256);
  float4 v = ((const float4*)src)[l];
  float ss = v.x * v.x + v.y * v.y + v.z * v.z + v.w * v.w;
#pragma unroll
  for (int m = 1; m < 64; m <<= 1) ss += __shfl_xor(ss, m, 64);
  float sc = SQRT_SCALE / fmaxf(sqrtf(ss), 1e-12f);
  ushort4 o;
  o.x = f2bf(v.x * sc); o.y = f2bf(v.y * sc);
  o.z = f2bf(v.z * sc); o.w = f2bf(v.w * sc);
  ((ushort4*)reps)[(size_t)row * 64 + l] = o;
  if (l == 0) denom[row] = 0.f;
  if (row == 0 && l == 0) out[0] = 0.f;
}

// Kernel B: strip-streaming upper-tri sim, 32x32x16 MFMA, counted-vmcnt pipeline.
// Block = (128-row strip it, 256-col chunk q); 4 waves x 32 rows; 32-col LDS tiles.
__global__ __launch_bounds__(256, 4) void ksim(const unsigned short* __restrict__ reps_,
                                               float* __restrict__ denom,
                                               float* __restrict__ pos) {
  __shared__ uint4 smem[2][1024];    // 2 x 32 rows x 512 B = 32 KB
  __shared__ float colacc[4][256];   // per-wave column accumulators, 4 KB
  const uint4* reps4 = (const uint4*)reps_;
  int tid = threadIdx.x, w = tid >> 6, l = tid & 63;
  int h = l >> 5;                    // K-half for 32x32x16 operands

  // ---- block -> (strip it, chunk q); chunks(it) = ceil((8192-128it)/256) ----
  int rem = blockIdx.x, it = 0, ch;
  while (rem >= (ch = (NROWS - 128 * it + 255) >> 8)) { rem -= ch; ++it; }
  int q = rem;
  int rowbase = it * 128;
  int cs0 = rowbase + q * 256;
  int niter = (NROWS - cs0) >> 5; if (niter > 8) niter = 8;

  // ---- zero colacc ----
#pragma unroll
  for (int i = 0; i < 4; ++i) ((float*)colacc)[tid + 256 * i] = 0.f;

  // ---- staging: 32 reps-rows x 512B -> 16KB buffer; linear dest, swizzled src ----
  auto stage = [&](int bufi, int colbase) {
#pragma unroll
    for (int i = 0; i < 4; ++i) {
      int c2 = w * 4 + i;            // 16 chunks of 1 KB (2 rows each)
      int lr = 2 * c2 + (l >> 5);
      int kb = ((l & 31) * 16) ^ ((lr & 7) << 4);
      gload_lds16((const char*)reps_ + (size_t)(colbase + lr) * 512 + kb,
                  (void*)&smem[bufi][c2 * 64]);
    }
  };
  stage(0, cs0);

  // ---- A fragments: wave w owns rows rowbase+32w..+32; lane holds row
  //      rowbase+32w+(l&31), k bytes [kk*32 + h*16, +16) ----
  bf16x8 a[16];
  {
    const uint4* base = reps4 + (size_t)(rowbase + w * 32 + (l & 31)) * 32 + h;
#pragma unroll
    for (int kk = 0; kk < 16; ++kk)
      a[kk] = __builtin_bit_cast(bf16x8, base[kk * 2]);
  }

  float rowsum[16];
#pragma unroll
  for (int i = 0; i < 16; ++i) rowsum[i] = 0.f;

  bool posChunk = (q == 16) && (it < 32);
  int buf = 0;
  for (int t = 0; t < niter; ++t) {
    // issue next stage, then wait ONLY for stage(t) (counted, never drains prefetch)
    if (t + 1 < niter) {
      stage(buf ^ 1, cs0 + 32 * (t + 1));
      asm volatile("s_waitcnt vmcnt(4)" ::: "memory");
    } else {
      asm volatile("s_waitcnt vmcnt(0)" ::: "memory");
    }
    __builtin_amdgcn_sched_barrier(0);
    __builtin_amdgcn_s_barrier();          // stage(t) visible to all waves
    __builtin_amdgcn_sched_barrier(0);

    f32x16 acc;
#pragma unroll
    for (int i = 0; i < 16; ++i) acc[i] = 0.f;
    __builtin_amdgcn_s_setprio(1);
#pragma unroll
    for (int kk = 0; kk < 16; ++kk) {
      int lr = l & 31;
      int kb = (kk * 32 + h * 16) ^ ((lr & 7) << 4);
      bf16x8 b = *(const bf16x8*)((const char*)&smem[buf][0] + lr * 512 + kb);
      acc = __builtin_amdgcn_mfma_f32_32x32x16_bf16(a[kk], b, acc, 0, 0, 0);
    }
    __builtin_amdgcn_s_setprio(0);

    // ---- epilogue: e=exp2(acc); diag mask; rowsum regs + colsum tree ----
    int cb = cs0 + 32 * t;
    int cg = cb + (l & 31);
    bool docol = !(q == 0 && t < 4);       // diag 128-col window: rowsum only
    bool dopos = posChunk && (t < 4);
    float csum = 0.f;
    int rbase = rowbase + w * 32 + 4 * h;
#pragma unroll
    for (int i = 0; i < 16; ++i) {
      int rg = rbase + (i & 3) + 8 * (i >> 2);
      float s = acc[i];
      float e = __builtin_amdgcn_exp2f(s);
      e = (rg == cg) ? 0.f : e;
      if (dopos && cg == rg + BROWS) pos[rg] = s;
      rowsum[i] += e;
      csum += e;
    }
    if (docol) {
      csum += __shfl_xor(csum, 32, 64);
      if (l < 32) colacc[w][(cb - cs0) + l] += csum;
    }
    __builtin_amdgcn_sched_barrier(0);
    __builtin_amdgcn_s_barrier();          // all reads of buf done -> reusable
    __builtin_amdgcn_sched_barrier(0);
    buf ^= 1;
  }

  // ---- row sums: reduce 32 lanes per half; 2 atomics per reg per wave ----
#pragma unroll
  for (int i = 0; i < 16; ++i) {
    float v = rowsum[i];
    v += __shfl_xor(v, 1, 64);
    v += __shfl_xor(v, 2, 64);
    v += __shfl_xor(v, 4, 64);
    v += __shfl_xor(v, 8, 64);
    v += __shfl_xor(v, 16, 64);
    if ((l & 31) == 0)
      atomicAdd(&denom[rowbase + w * 32 + 4 * h + (i & 3) + 8 * (i >> 2)], v);
  }

  // ---- col sums: combine 4 wave regions, one atomic per column ----
  __syncthreads();
  {
    float v = colacc[0][tid & 255] + colacc[1][tid & 255] +
              colacc[2][tid & 255] + colacc[3][tid & 255];
    int col = cs0 + (tid & 255);
    if (col < NROWS && v != 0.f) atomicAdd(&denom[col], v);
  }
}

// Kernel F: + (1/N) * sum_i (log(denom_i) - posS_{i mod B} * ln2)
__global__ __launch_bounds__(256) void kfin(const float* __restrict__ denom,
                                            const float* __restrict__ pos,
                                            float* __restrict__ out) {
  int i = blockIdx.x * 256 + threadIdx.x;
  float v = (logf(denom[i]) - pos[i & 4095] * LN2) * (1.0f / 8192.0f);
#pragma unroll
  for (int m = 1; m < 64; m <<= 1) v += __shfl_xor(v, m, 64);
  __shared__ float part[4];
  if ((threadIdx.x & 63) == 0) part[threadIdx.x >> 6] = v;
  __syncthreads();
  if (threadIdx.x == 0)
    atomicAdd(out, part[0] + part[1] + part[2] + part[3]);
}

extern "C" void kernel_launch(void* const* d_in, const int* in_sizes, int n_in,
                              void* d_out, int out_size, void* d_ws, size_t ws_size,
                              hipStream_t stream) {
  (void)in_sizes; (void)n_in; (void)out_size; (void)ws_size;
  const float* zi = (const float*)d_in[0];
  const float* zj = (const float*)d_in[1];
  float* out = (float*)d_out;
  char* ws = (char*)d_ws;
  unsigned short* reps = (unsigned short*)ws;                 // 4 MB
  float* denom = (float*)(ws + 4194304);                      // 32 KB
  float* pos   = (float*)(ws + 4194304 + 32768);              // 16 KB

  knorm<<<2048, 256, 0, stream>>>(zi, zj, reps, denom, out);
  ksim<<<NBLK, 256, 0, stream>>>(reps, denom, pos);
  kfin<<<32, 256, 0, stream>>>(denom, pos, out);
}

// Round 6
// 55.686 us; speedup vs baseline: 1.2337x; 1.2337x over previous
//
#include <hip/hip_runtime.h>
#include <hip/hip_bf16.h>
#include <stdint.h>

#define NROWS 8192
#define BROWS 4096
#define SQRT_SCALE 3.7982826f   // sqrt((1/T)*log2(e)), T=0.1
#define LN2 0.6931471805599453f
#define NBLK 1056               // sum_{it=0}^{63} ceil((8192-128it)/256)

typedef __attribute__((ext_vector_type(8))) short bf16x8;
typedef __attribute__((ext_vector_type(4))) float f32x4;

__device__ inline void gload_lds16(const void* g, void* l) {
  __builtin_amdgcn_global_load_lds((const __attribute__((address_space(1))) void*)g,
                                   (__attribute__((address_space(3))) void*)l,
                                   16, 0, 0);
}

__device__ inline unsigned short f2bf(float x) {
  __hip_bfloat16 h = __float2bfloat16(x);
  return __builtin_bit_cast(unsigned short, h);
}

// Kernel A: L2-normalize rows, scale by sqrt((1/T)log2e), -> bf16 reps; zero denom/out.
__global__ __launch_bounds__(256) void knorm(const float* __restrict__ zi,
                                             const float* __restrict__ zj,
                                             unsigned short* __restrict__ reps,
                                             float* __restrict__ denom,
                                             float* __restrict__ out) {
  int w = threadIdx.x >> 6, l = threadIdx.x & 63;
  int row = blockIdx.x * 4 + w;
  const float* src = (row < BROWS) ? (zi + (size_t)row * 256)
                                   : (zj + (size_t)(row - BROWS) * 256);
  float4 v = ((const float4*)src)[l];
  float ss = v.x * v.x + v.y * v.y + v.z * v.z + v.w * v.w;
#pragma unroll
  for (int m = 1; m < 64; m <<= 1) ss += __shfl_xor(ss, m, 64);
  float sc = SQRT_SCALE / fmaxf(sqrtf(ss), 1e-12f);
  ushort4 o;
  o.x = f2bf(v.x * sc); o.y = f2bf(v.y * sc);
  o.z = f2bf(v.z * sc); o.w = f2bf(v.w * sc);
  ((ushort4*)reps)[(size_t)row * 64 + l] = o;
  if (l == 0) denom[row] = 0.f;
  if (row == 0 && l == 0) out[0] = 0.f;
}

// Kernel B: strip-streaming upper-tri sim. R4 compute core (16x16 MFMA, 4 acc
// chains, conflict-free 16-lane B reads) + counted-vmcnt raw-barrier pipeline.
// Block = (128-row strip it, 256-col chunk q); 4 waves x 32 rows; 32-col tiles.
__global__ __launch_bounds__(256, 4) void ksim(const unsigned short* __restrict__ reps_,
                                               float* __restrict__ denom,
                                               float* __restrict__ pos) {
  __shared__ uint4 smem[2][1024];    // 2 x 32 rows x 512 B = 32 KB
  __shared__ float colacc[4][256];   // per-wave column accumulators, 4 KB
  const uint4* reps4 = (const uint4*)reps_;
  int tid = threadIdx.x, w = tid >> 6, l = tid & 63;
  int kgrp = l >> 4;

  // ---- block -> (strip it, chunk q); chunks(it) = ceil((8192-128it)/256) ----
  int rem = blockIdx.x, it = 0, ch;
  while (rem >= (ch = (NROWS - 128 * it + 255) >> 8)) { rem -= ch; ++it; }
  int q = rem;
  int rowbase = it * 128;
  int cs0 = rowbase + q * 256;
  int niter = (NROWS - cs0) >> 5; if (niter > 8) niter = 8;

  // ---- zero colacc ----
#pragma unroll
  for (int i = 0; i < 4; ++i) ((float*)colacc)[tid + 256 * i] = 0.f;

  // ---- staging: 32 reps-rows x 512B -> 16KB buffer; linear dest, swizzled src ----
  auto stage = [&](int bufi, int colbase) {
#pragma unroll
    for (int i = 0; i < 4; ++i) {
      int c2 = w * 4 + i;            // 16 chunks of 1 KB (2 rows each)
      int lr = 2 * c2 + (l >> 5);
      int kb = ((l & 31) * 16) ^ ((lr & 7) << 4);
      gload_lds16((const char*)reps_ + (size_t)(colbase + lr) * 512 + kb,
                  (void*)&smem[bufi][c2 * 64]);
    }
  };
  stage(0, cs0);    // oldest in-flight group

  // ---- A fragments: wave w owns rows rowbase+32w..+32; lane holds row
  //      +fr*16+(l&15), k bytes [kk*64 + kgrp*16, +16) ----
  bf16x8 a[2][8];
  int arow = rowbase + w * 32 + (l & 15);
#pragma unroll
  for (int fr = 0; fr < 2; ++fr) {
    const uint4* base = reps4 + (size_t)(arow + fr * 16) * 32 + kgrp;
#pragma unroll
    for (int kk = 0; kk < 8; ++kk)
      a[fr][kk] = __builtin_bit_cast(bf16x8, base[kk * 4]);
  }

  float rowsum[2][4];
#pragma unroll
  for (int fr = 0; fr < 2; ++fr)
#pragma unroll
    for (int r = 0; r < 4; ++r) rowsum[fr][r] = 0.f;

  bool posChunk = (q == 16) && (it < 32);
  int r0 = rowbase + w * 32 + kgrp * 4;
  int buf = 0;

  for (int t = 0; t < niter; ++t) {
    // issue next stage, then wait ONLY for stage(t) (+A-loads at t=0);
    // stage(t+1)'s 4 loads stay in flight across the barrier and compute.
    if (t + 1 < niter) {
      stage(buf ^ 1, cs0 + 32 * (t + 1));
      asm volatile("s_waitcnt vmcnt(4)" ::: "memory");
    } else {
      asm volatile("s_waitcnt vmcnt(0)" ::: "memory");
    }
    __builtin_amdgcn_sched_barrier(0);
    __builtin_amdgcn_s_barrier();          // stage(t) visible to all waves
    __builtin_amdgcn_sched_barrier(0);

    // ---- MFMA: K=256, 8 steps; 2 ds_read_b128 + 4 MFMA per step per wave ----
    f32x4 acc[2][2];
    const f32x4 zero = {0.f, 0.f, 0.f, 0.f};
    __builtin_amdgcn_s_setprio(1);
#pragma unroll
    for (int kk = 0; kk < 8; ++kk) {
      int kb = kk * 64 + kgrp * 16;
      int lr0 = (l & 15);
      int lr1 = 16 + (l & 15);
      bf16x8 b0 = *(const bf16x8*)&smem[buf][lr0 * 32 + ((kb ^ ((lr0 & 7) << 4)) >> 4)];
      bf16x8 b1 = *(const bf16x8*)&smem[buf][lr1 * 32 + ((kb ^ ((lr1 & 7) << 4)) >> 4)];
#pragma unroll
      for (int fr = 0; fr < 2; ++fr) {
        if (kk == 0) {
          acc[fr][0] = __builtin_amdgcn_mfma_f32_16x16x32_bf16(a[fr][0], b0, zero, 0, 0, 0);
          acc[fr][1] = __builtin_amdgcn_mfma_f32_16x16x32_bf16(a[fr][0], b1, zero, 0, 0, 0);
        } else {
          acc[fr][0] = __builtin_amdgcn_mfma_f32_16x16x32_bf16(a[fr][kk], b0, acc[fr][0], 0, 0, 0);
          acc[fr][1] = __builtin_amdgcn_mfma_f32_16x16x32_bf16(a[fr][kk], b1, acc[fr][1], 0, 0, 0);
        }
      }
    }
    __builtin_amdgcn_s_setprio(0);

    // ---- epilogue: e=exp2(acc), diag mask, rowsum + col partials ----
    int cb = cs0 + 32 * t;
    bool docol = !(q == 0 && t < 4);       // diag 128-col window: rowsum only
    bool dopos = posChunk && (t < 4);
    float cp0 = 0.f, cp1 = 0.f;
    int cbase = cb + (l & 15);
#pragma unroll
    for (int fr = 0; fr < 2; ++fr)
#pragma unroll
      for (int fc = 0; fc < 2; ++fc)
#pragma unroll
        for (int r = 0; r < 4; ++r) {
          int rg = r0 + fr * 16 + r;
          int cg = cbase + fc * 16;
          float s = acc[fr][fc][r];
          float e = __builtin_amdgcn_exp2f(s);
          e = (rg == cg) ? 0.f : e;
          if (dopos && cg == rg + BROWS) pos[rg] = s;
          rowsum[fr][r] += e;
          if (fc == 0) cp0 += e; else cp1 += e;
        }
    if (docol) {
      cp0 += __shfl_xor(cp0, 16, 64); cp0 += __shfl_xor(cp0, 32, 64);
      cp1 += __shfl_xor(cp1, 16, 64); cp1 += __shfl_xor(cp1, 32, 64);
      if (l < 16) {
        int off = (cb - cs0) + l;
        colacc[w][off] += cp0;
        colacc[w][off + 16] += cp1;
      }
    }
    __builtin_amdgcn_sched_barrier(0);
    __builtin_amdgcn_s_barrier();          // all reads of buf done -> reusable
    __builtin_amdgcn_sched_barrier(0);
    buf ^= 1;
  }

  // ---- row sums: reduce 16 col-lanes; 4 lanes atomic per wave ----
#pragma unroll
  for (int fr = 0; fr < 2; ++fr)
#pragma unroll
    for (int r = 0; r < 4; ++r) {
      float v = rowsum[fr][r];
      v += __shfl_xor(v, 1, 64);
      v += __shfl_xor(v, 2, 64);
      v += __shfl_xor(v, 4, 64);
      v += __shfl_xor(v, 8, 64);
      if ((l & 15) == 0) atomicAdd(&denom[r0 + fr * 16 + r], v);
    }

  // ---- col sums: combine 4 wave regions, one atomic per column ----
  __syncthreads();
  {
    float v = colacc[0][tid & 255] + colacc[1][tid & 255] +
              colacc[2][tid & 255] + colacc[3][tid & 255];
    int col = cs0 + (tid & 255);
    if (col < NROWS && v != 0.f) atomicAdd(&denom[col], v);
  }
}

// Kernel F: + (1/N) * sum_i (log(denom_i) - posS_{i mod B} * ln2)
__global__ __launch_bounds__(256) void kfin(const float* __restrict__ denom,
                                            const float* __restrict__ pos,
                                            float* __restrict__ out) {
  int i = blockIdx.x * 256 + threadIdx.x;
  float v = (logf(denom[i]) - pos[i & 4095] * LN2) * (1.0f / 8192.0f);
#pragma unroll
  for (int m = 1; m < 64; m <<= 1) v += __shfl_xor(v, m, 64);
  __shared__ float part[4];
  if ((threadIdx.x & 63) == 0) part[threadIdx.x >> 6] = v;
  __syncthreads();
  if (threadIdx.x == 0)
    atomicAdd(out, part[0] + part[1] + part[2] + part[3]);
}

extern "C" void kernel_launch(void* const* d_in, const int* in_sizes, int n_in,
                              void* d_out, int out_size, void* d_ws, size_t ws_size,
                              hipStream_t stream) {
  (void)in_sizes; (void)n_in; (void)out_size; (void)ws_size;
  const float* zi = (const float*)d_in[0];
  const float* zj = (const float*)d_in[1];
  float* out = (float*)d_out;
  char* ws = (char*)d_ws;
  unsigned short* reps = (unsigned short*)ws;                 // 4 MB
  float* denom = (float*)(ws + 4194304);                      // 32 KB
  float* pos   = (float*)(ws + 4194304 + 32768);              // 16 KB

  knorm<<<2048, 256, 0, stream>>>(zi, zj, reps, denom, out);
  ksim<<<NBLK, 256, 0, stream>>>(reps, denom, pos);
  kfin<<<32, 256, 0, stream>>>(denom, pos, out);
}